// Round 11
// baseline (584.801 us; speedup 1.0000x reference)
//
#include <hip/hip_runtime.h>
#include <hip/hip_bf16.h>

#define D_DIM 1024
#define H_DIM 4096
#define E_NUM 8
#define T_TOK 8192
#define CAPN 2252
#define CAP_PAD 2304   // 18 * 128
#define MT 18

typedef __attribute__((ext_vector_type(8))) short short8;
typedef __attribute__((ext_vector_type(4))) float f32x4;
typedef __attribute__((ext_vector_type(4))) float f4v;   // NT-capable float4
typedef const __attribute__((address_space(1))) void* gas_ptr;
typedef __attribute__((address_space(3))) void* las_ptr;

__device__ __forceinline__ unsigned short f2bf(float f) {
    __hip_bfloat16 h = __float2bfloat16(f);
    return __builtin_bit_cast(unsigned short, h);
}

// ---- Fused prep: router (blocks 0..2047) + chunk W2 (next 8192) + chunk W1 (next 8192) ----
// All three are mutually independent; fusing removes 2 launch gaps and co-schedules the
// short router with the HBM-bound weight chunking.
__global__ __launch_bounds__(256) void prep_kernel(
    const float* __restrict__ x,
    const float* __restrict__ noise,
    const float* __restrict__ Wr,
    const float* __restrict__ br,
    const float* __restrict__ Wn,
    const float* __restrict__ bn,
    __hip_bfloat16* __restrict__ xb,
    int* __restrict__ tok_e,
    float* __restrict__ tok_g,
    const float* __restrict__ W1,
    const float* __restrict__ W2,
    ushort* __restrict__ w1c,
    ushort* __restrict__ w2c)
{
    __shared__ float tile[64][65];
    const unsigned blk = blockIdx.x;

    if (blk < 2048) {
        // ---------------- Router: logits, noisy top-2, gates; fuses x -> bf16 ----------------
        const int l = threadIdx.x & 63;
        const int w = threadIdx.x >> 6;
        const int t = blk * 4 + w;
        const float* xr = x + (size_t)t * D_DIM;

        float ar[8] = {0,0,0,0,0,0,0,0};
        float an[8] = {0,0,0,0,0,0,0,0};
#pragma unroll
        for (int i = 0; i < 4; ++i) {
            int d = i * 256 + l * 4;
            f4v xv = __builtin_nontemporal_load((const f4v*)(xr + d));   // read-once stream
            ushort4 xq;
            xq.x = f2bf(xv.x); xq.y = f2bf(xv.y); xq.z = f2bf(xv.z); xq.w = f2bf(xv.w);
            *(ushort4*)(xb + (size_t)t * D_DIM + d) = xq;                // cached: re-read by gather
            float xs[4] = {xv.x, xv.y, xv.z, xv.w};
#pragma unroll
            for (int j = 0; j < 4; ++j) {
                const float* wrp = Wr + (size_t)(d + j) * 8;
                float4 wa = *(const float4*)wrp;
                float4 wb = *(const float4*)(wrp + 4);
                ar[0] = fmaf(xs[j], wa.x, ar[0]); ar[1] = fmaf(xs[j], wa.y, ar[1]);
                ar[2] = fmaf(xs[j], wa.z, ar[2]); ar[3] = fmaf(xs[j], wa.w, ar[3]);
                ar[4] = fmaf(xs[j], wb.x, ar[4]); ar[5] = fmaf(xs[j], wb.y, ar[5]);
                ar[6] = fmaf(xs[j], wb.z, ar[6]); ar[7] = fmaf(xs[j], wb.w, ar[7]);
                const float* wnp = Wn + (size_t)(d + j) * 8;
                float4 na = *(const float4*)wnp;
                float4 nb = *(const float4*)(wnp + 4);
                an[0] = fmaf(xs[j], na.x, an[0]); an[1] = fmaf(xs[j], na.y, an[1]);
                an[2] = fmaf(xs[j], na.z, an[2]); an[3] = fmaf(xs[j], na.w, an[3]);
                an[4] = fmaf(xs[j], nb.x, an[4]); an[5] = fmaf(xs[j], nb.y, an[5]);
                an[6] = fmaf(xs[j], nb.z, an[6]); an[7] = fmaf(xs[j], nb.w, an[7]);
            }
        }
#pragma unroll
        for (int e = 0; e < 8; ++e) {
#pragma unroll
            for (int s = 32; s > 0; s >>= 1) {
                ar[e] += __shfl_xor(ar[e], s, 64);
                an[e] += __shfl_xor(an[e], s, 64);
            }
        }
        if (l == 0) {
            float nv[8];
#pragma unroll
            for (int e = 0; e < 8; ++e) {
                float z = an[e] + bn[e];
                float sp = fmaxf(z, 0.f) + log1pf(expf(-fabsf(z)));   // softplus, stable
                nv[e] = ar[e] + br[e] + noise[(size_t)t * 8 + e] * sp;
            }
            int e0 = 0; float v0 = nv[0];
#pragma unroll
            for (int e = 1; e < 8; ++e) if (nv[e] > v0) { v0 = nv[e]; e0 = e; }  // ties -> lower idx
            int e1 = -1; float v1 = -3.4e38f;
#pragma unroll
            for (int e = 0; e < 8; ++e) if (e != e0 && nv[e] > v1) { v1 = nv[e]; e1 = e; }
            float ex = expf(v1 - v0);          // v1 <= v0, no overflow
            float p0 = 1.f / (1.f + ex);
            float p1 = ex * p0;
            tok_e[2 * t]     = e0; tok_e[2 * t + 1] = e1;
            tok_g[2 * t]     = p0; tok_g[2 * t + 1] = p1;
        }
        return;
    }

    // ---- Weight chunking: W[e][K][N] f32 -> Wc[e][K/8][N][8] bf16 ----
    const float* src; ushort* dstb; int K, N; unsigned i;
    if (blk < 2048 + 8192) { i = blk - 2048;  K = H_DIM; N = D_DIM; src = W2; dstb = w2c; }
    else                   { i = blk - 10240; K = D_DIM; N = H_DIM; src = W1; dstb = w1c; }
    const int nx = N >> 6;
    const int bx = i % nx;
    const unsigned rem = i / nx;
    const int by = rem % (K >> 6);
    const int e  = rem / (K >> 6);
    const int k0 = by * 64, n0 = bx * 64;
    const float* s = src + (size_t)e * K * N;
    ushort* dst = dstb + (size_t)e * (K / 8) * N * 8;
    const int t = threadIdx.x;
    const int rr = t >> 4, c4 = (t & 15) * 4;
#pragma unroll
    for (int p = 0; p < 4; ++p) {
        int r = p * 16 + rr;
        f4v v = __builtin_nontemporal_load(
            (const f4v*)(s + (size_t)(k0 + r) * N + n0 + c4));   // read-once f32 stream
        tile[r][c4]     = v.x; tile[r][c4 + 1] = v.y;
        tile[r][c4 + 2] = v.z; tile[r][c4 + 3] = v.w;
    }
    __syncthreads();
    const int n = t & 63, kc = t >> 6;
#pragma unroll
    for (int p = 0; p < 2; ++p) {
        int kcc = p * 4 + kc;
        ushort g[8];
#pragma unroll
        for (int j = 0; j < 8; ++j) g[j] = f2bf(tile[kcc * 8 + j][n]);
        *(short8*)(dst + ((size_t)(k0 / 8 + kcc) * N + n0 + n) * 8) = *(const short8*)g;  // cached
    }
}

// ---------- Capacity scan: wave e compacts its tokens in order; lb_loss sums ----------
__global__ void scan_kernel(const int* __restrict__ tok_e,
                            const float* __restrict__ tok_g,
                            int* __restrict__ routed,
                            int* __restrict__ inv,
                            int* __restrict__ nkept,
                            float* __restrict__ lb_out)
{
    const int e = threadIdx.x >> 6;
    const int l = threadIdx.x & 63;
    __shared__ float s_g[E_NUM];
    __shared__ int   s_c[E_NUM];

    int run = 0;
    float gsum = 0.f;
    for (int b = 0; b < 8; ++b) {
        int2  ev[16];
        float2 gv[16];
#pragma unroll
        for (int c = 0; c < 16; ++c) {
            int t = (b * 16 + c) * 64 + l;
            ev[c] = ((const int2*)tok_e)[t];
            gv[c] = ((const float2*)tok_g)[t];
        }
#pragma unroll
        for (int c = 0; c < 16; ++c) {
            int t = (b * 16 + c) * 64 + l;
            int j = (ev[c].x == e) ? 0 : ((ev[c].y == e) ? 1 : -1);
            bool sel = (j >= 0);
            unsigned long long m = __ballot(sel);
            if (sel) {
                int pos = run + __popcll(m & ((1ull << l) - 1ull));
                if (pos < CAPN) {
                    routed[e * CAP_PAD + pos] = t;
                    inv[2 * t + j] = e * CAP_PAD + pos;
                }
                gsum += (j == 0) ? gv[c].x : gv[c].y;   // pre-capacity, matches reference lb
            }
            run += __popcll(m);
        }
    }
#pragma unroll
    for (int s = 32; s > 0; s >>= 1) gsum += __shfl_xor(gsum, s, 64);
    int nk = min(run, CAPN);
    for (int s = nk + l; s < CAP_PAD; s += 64) routed[e * CAP_PAD + s] = 0;  // safe pad
    if (l == 0) { nkept[e] = nk; s_g[e] = gsum; s_c[e] = run; }
    __syncthreads();
    if (threadIdx.x == 0) {
        float lb = 0.f;
        for (int ee = 0; ee < E_NUM; ++ee)
            lb += (s_g[ee] / (float)T_TOK) * ((float)s_c[ee] / (float)T_TOK);
        lb_out[0] = lb * (float)E_NUM;
    }
}

// ---- Gather: xg[e][D/8][CAP_PAD][8] bf16 <- xb[routed[e][m]][dc*8..+8] ----
__global__ void gather_kernel(const ushort* __restrict__ xb,
                              const int* __restrict__ routed,
                              ushort* __restrict__ xg)
{
    const int dc = blockIdx.x & 127;
    const int e  = blockIdx.x >> 7;
    ushort* dst = xg + (size_t)(e * 128 + dc) * CAP_PAD * 8;
    const int* rte = routed + e * CAP_PAD;
#pragma unroll
    for (int p = 0; p < 9; ++p) {
        int m = p * 256 + threadIdx.x;
        int tok = rte[m];
        ulonglong2 v = *(const ulonglong2*)(xb + (size_t)tok * D_DIM + dc * 8);
        *(ulonglong2*)(dst + (size_t)m * 8) = v;   // cached: re-read by GEMM1
    }
}

// ---------- Expert GEMM: 128x128 tile, BK=32, 4 waves, 3-stage pipeline, 3 blocks/CU ----------
// r7 compute structure + r7 plain XCD swizzle (r9/r10's bn-clustering cost ~12us/GEMM:
// traffic reduction bought no time -> placement perturbation was net negative).
// Cached epilogue stores (r9's NT scalar stores regressed). Staging addresses
// strength-reduced: running uniform offsets advanced per K-tile.
template <int MODE>
__global__ __launch_bounds__(256, 3) void ffn_gemm(
    const ushort* __restrict__ A,     // [E][KD/8][CAP_PAD][8]
    const ushort* __restrict__ Bt,    // [E][KD/8][ND][8]
    const float* __restrict__ bias,
    const int* __restrict__ nkept,
    ushort* __restrict__ outH,
    float*  __restrict__ outP,
    int sshift, int nkt)
{
    constexpr int KD = (MODE == 1) ? D_DIM : H_DIM;
    constexpr int ND = (MODE == 1) ? H_DIM : D_DIM;
    constexpr int NC = KD / 8;
    __shared__ ushort lds[24576];   // 48 KiB = 3 stages x 16KB

    // Plain XCD-aware swizzle (total blocks always % 8 == 0 here)
    unsigned total = gridDim.x * gridDim.y * gridDim.z;
    unsigned flat  = blockIdx.x + gridDim.x * (blockIdx.y + gridDim.y * blockIdx.z);
    unsigned sw    = (flat & 7) * (total >> 3) + (flat >> 3);
    unsigned bn    = sw % gridDim.x;
    unsigned t1    = sw / gridDim.x;
    unsigned bm    = t1 % gridDim.y;
    unsigned bz    = t1 / gridDim.y;

    const int e  = (int)(bz >> sshift);
    const int sp = (int)(bz & ((1u << sshift) - 1u));
    const int m0 = (int)bm * 128, n0 = (int)bn * 128;
    if (m0 >= nkept[e]) return;
    const int kc0 = sp * (nkt << 2);   // first k-chunk of this split (4 chunks / K-tile)

    const int tid  = threadIdx.x;
    const int lane = tid & 63;
    const int w    = tid >> 6;           // 0..3
    const int chi  = w >> 1;             // chunk selector: waves 0,1 -> {0,2}; 2,3 -> {1,3}
    const int rhE  = (w & 1) * 64;       // row-half (global, elements)
    const int rhB  = (w & 1) * 1024;     // row-half (LDS bytes)

    const size_t sAc = (size_t)CAP_PAD * 8;   // chunk stride (ushorts)
    const size_t sBc = (size_t)ND * 8;
    const size_t tsA = 4 * sAc;               // K-tile stride (ushorts)
    const size_t tsB = 4 * sBc;

    const ushort* Ab = A  + ((size_t)e * NC * CAP_PAD + (size_t)(m0 + rhE + lane)) * 8
                          + (size_t)kc0 * sAc;
    const ushort* Bb = Bt + ((size_t)e * NC * ND + (size_t)(n0 + rhE + lane)) * 8
                          + (size_t)kc0 * sBc;
    const ushort* A0 = Ab + (size_t)chi * sAc;
    const ushort* A2 = Ab + (size_t)(2 + chi) * sAc;
    const ushort* B0 = Bb + (size_t)chi * sBc;
    const ushort* B2 = Bb + (size_t)(2 + chi) * sBc;

    auto gl = [&](const ushort* g, int ldsbyte) {
        __builtin_amdgcn_global_load_lds((gas_ptr)g, (las_ptr)((char*)lds + ldsbyte), 16, 0, 0);
    };
    auto issueA = [&](size_t off, int stB) {
        gl(A0 + off, stB + chi * 2048 + rhB);
        gl(A2 + off, stB + (2 + chi) * 2048 + rhB);
    };
    auto issueB = [&](size_t off, int stB) {
        gl(B0 + off, stB + 8192 + chi * 2048 + rhB);
        gl(B2 + off, stB + 8192 + (2 + chi) * 2048 + rhB);
    };

    // Prologue: tiles 0,1 -> stages 0,1. Wait only for tile 0 (vmcnt(4)), keep 1 in flight.
    issueA(0, 0);        issueB(0, 0);
    issueA(tsA, 16384);  issueB(tsB, 16384);
    asm volatile("s_waitcnt vmcnt(4)" ::: "memory");
    __builtin_amdgcn_s_barrier();

    f32x4 acc[4][4] = {};
    const int wm = (w >> 1) * 64;
    const int wn = (w & 1) * 64;
    const int fr = lane & 15;
    const int fq = lane >> 4;

    int rdS = 0;              // ushort index of read stage (stride 8192 = 16KB)
    int wrB = 32768;          // byte offset of write stage ((kt+2)%3)
    size_t oA = 2 * tsA;      // prefetch offset for tile kt+2 (clamped via cond. advance)
    size_t oB = 2 * tsB;

    for (int kt = 0; kt < nkt; ++kt) {
        const ushort* Ard = lds + rdS;
        const ushort* Brd = Ard + 4096;

        short8 af[4], bfr[4];
#pragma unroll
        for (int j = 0; j < 4; ++j)
            bfr[j] = *(const short8*)(Brd + fq * 1024 + (wn + j * 16 + fr) * 8);
#pragma unroll
        for (int i = 0; i < 4; ++i)
            af[i] = *(const short8*)(Ard + fq * 1024 + (wm + i * 16 + fr) * 8);

        issueA(oA, wrB);
        issueB(oB, wrB);

        __builtin_amdgcn_s_setprio(1);
#pragma unroll
        for (int i = 0; i < 4; ++i)
#pragma unroll
            for (int j = 0; j < 4; ++j)
                acc[i][j] = __builtin_amdgcn_mfma_f32_16x16x32_bf16(af[i], bfr[j], acc[i][j], 0, 0, 0);
        __builtin_amdgcn_s_setprio(0);

        asm volatile("s_waitcnt vmcnt(4)" ::: "memory");   // K-tile kt+1 resident
        __builtin_amdgcn_s_barrier();

        rdS = (rdS == 16384) ? 0 : rdS + 8192;
        wrB = (wrB == 32768) ? 0 : wrB + 16384;
        if (kt < nkt - 3) { oA += tsA; oB += tsB; }   // clamp: last tiles re-stage nkt-1
    }

    // ---- epilogue (cached stores) ----
#pragma unroll
    for (int j = 0; j < 4; ++j) {
        int nc = n0 + wn + j * 16 + fr;
        float bv = (MODE == 1) ? bias[e * ND + nc] : 0.f;
#pragma unroll
        for (int i = 0; i < 4; ++i) {
            int mr = m0 + wm + i * 16 + (fq << 2);
#pragma unroll
            for (int r = 0; r < 4; ++r) {
                float v = acc[i][j][r] + bv;
                if (MODE == 1) {
                    v = fmaxf(v, 0.f);
                    // hbuf chunked: [e][H/8][CAP_PAD][8]
                    outH[(((size_t)e * 512 + (nc >> 3)) * CAP_PAD + mr + r) * 8 + (nc & 7)] = f2bf(v);
                } else {
                    outP[((size_t)(sp * E_NUM + e) * CAP_PAD + mr + r) * D_DIM + nc] = v;
                }
            }
        }
    }
}

// -------- Final combine: out[t] = sum_j gate_j * (sum_s part[s][inv_j] + b2[e_j]) --------
__global__ void combine_kernel(const float* __restrict__ part,
                               const int* __restrict__ inv,
                               const float* __restrict__ tok_g,
                               const float* __restrict__ b2,
                               int S,
                               float* __restrict__ out)
{
    const int t = blockIdx.x;
    const int d = threadIdx.x * 4;
    f4v r = {0.f, 0.f, 0.f, 0.f};
#pragma unroll
    for (int j = 0; j < 2; ++j) {
        int i = inv[2 * t + j];
        if (i >= 0) {
            float g = tok_g[2 * t + j];
            int e = i / CAP_PAD;
            f4v a = *(const f4v*)(b2 + (size_t)e * D_DIM + d);
            for (int s = 0; s < S; ++s) {
                f4v p = __builtin_nontemporal_load(
                    (const f4v*)(part + ((size_t)s * E_NUM * CAP_PAD + i) * D_DIM + d));
                a += p;
            }
            r += g * a;
        }
    }
    __builtin_nontemporal_store(r, (f4v*)(out + (size_t)t * D_DIM + d));
}

extern "C" void kernel_launch(void* const* d_in, const int* in_sizes, int n_in,
                              void* d_out, int out_size, void* d_ws, size_t ws_size,
                              hipStream_t stream)
{
    const float* x  = (const float*)d_in[0];
    const float* nz = (const float*)d_in[1];
    const float* Wr = (const float*)d_in[2];
    const float* br = (const float*)d_in[3];
    const float* Wn = (const float*)d_in[4];
    const float* bn = (const float*)d_in[5];
    const float* W1 = (const float*)d_in[6];
    const float* b1 = (const float*)d_in[7];
    const float* W2 = (const float*)d_in[8];
    const float* b2 = (const float*)d_in[9];
    float* out = (float*)d_out;
    char* ws = (char*)d_ws;

    // Workspace: [w2c 64MB][hbuf 144MB][small 1MB][dyn]
    //   dyn phase1: xg(36MB) + xb(16MB) + w1c(64MB)   (all dead after GEMM1)
    //   dyn phase2: part (S * 75.5MB)                 (overlays phase1)
    const size_t sz_w2c = (size_t)E_NUM * (H_DIM / 8) * D_DIM * 8 * 2;   // 67,108,864
    const size_t sz_h   = (size_t)E_NUM * 512 * CAP_PAD * 8 * 2;         // 150,994,944
    const size_t o_w2c  = 0;
    const size_t o_h    = o_w2c + sz_w2c;
    const size_t o_sm   = o_h + sz_h;
    const size_t o_dyn  = o_sm + (1u << 20);
    const size_t sz_xg  = (size_t)E_NUM * 128 * CAP_PAD * 8 * 2;         // 37,748,736
    const size_t sz_xb  = (size_t)T_TOK * D_DIM * 2;                     // 16,777,216
    const size_t sz_w1c = (size_t)E_NUM * (D_DIM / 8) * H_DIM * 8 * 2;   // 67,108,864
    const size_t sz_p1  = sz_xg + sz_xb + sz_w1c;                        // 121,634,816
    const size_t sz_part1 = (size_t)E_NUM * CAP_PAD * D_DIM * 4;         // 75,497,472

    int sshift = 1;
    while (sshift > 0) {
        size_t need = o_dyn + ((sz_part1 << sshift) > sz_p1 ? (sz_part1 << sshift) : sz_p1);
        if (need <= ws_size) break;
        --sshift;
    }
    const int S = 1 << sshift;

    ushort* w2c  = (ushort*)(ws + o_w2c);
    ushort* hbuf = (ushort*)(ws + o_h);
    int*    rt   = (int*)(ws + o_sm);
    int*    te   = (int*)(ws + o_sm + 131072);
    float*  tg   = (float*)(ws + o_sm + 262144);
    int*    inv  = (int*)(ws + o_sm + 393216);
    int*    nk   = (int*)(ws + o_sm + 524288);
    ushort* xg   = (ushort*)(ws + o_dyn);
    ushort* xb   = (ushort*)(ws + o_dyn + sz_xg);
    ushort* w1c  = (ushort*)(ws + o_dyn + sz_xg + sz_xb);
    float*  part = (float*)(ws + o_dyn);   // overlays xg/xb/w1c (dead after GEMM1)

    (void)hipMemsetAsync(inv, 0xFF, (size_t)T_TOK * 2 * 4, stream);   // inv = -1

    // Fused router + chunkW2 + chunkW1 (independent; removes 2 launch gaps)
    prep_kernel<<<2048 + 2 * 8192, 256, 0, stream>>>(
        x, nz, Wr, br, Wn, bn, (__hip_bfloat16*)xb, te, tg, W1, W2, w1c, w2c);

    scan_kernel<<<1, 512, 0, stream>>>(te, tg, rt, inv, nk, out + (size_t)T_TOK * D_DIM);
    gather_kernel<<<E_NUM * 128, 256, 0, stream>>>(xb, rt, xg);

    // GEMM1: per expert [2304 x 1024] @ [1024 x 4096] -> hbuf chunked (bf16, relu+b1)
    // 32x18x8 = 4608 blocks = exactly 6 rounds at 3 blocks/CU.
    ffn_gemm<1><<<dim3(H_DIM / 128, MT, E_NUM), 256, 0, stream>>>(
        xg, w1c, b1, nk, hbuf, nullptr, 0, D_DIM / 32);

    // GEMM2: per expert [2304 x 4096] @ [4096 x 1024], split-K=S -> f32 partials
    // 8x18x16 = 2304 blocks = exactly 3 rounds at 3 blocks/CU.
    ffn_gemm<2><<<dim3(D_DIM / 128, MT, E_NUM << sshift), 256, 0, stream>>>(
        hbuf, w2c, nullptr, nk, nullptr, part, sshift, (H_DIM / 32) >> sshift);

    combine_kernel<<<T_TOK, 256, 0, stream>>>(part, inv, tg, b2, S, out);
}

// Round 12
// 564.771 us; speedup vs baseline: 1.0355x; 1.0355x over previous
//
#include <hip/hip_runtime.h>
#include <hip/hip_bf16.h>

#define D_DIM 1024
#define H_DIM 4096
#define E_NUM 8
#define T_TOK 8192
#define CAPN 2252
#define CAP_PAD 2304   // 9 * 256
#define MT 9

typedef __attribute__((ext_vector_type(8))) short short8;
typedef __attribute__((ext_vector_type(4))) float f32x4;
typedef __attribute__((ext_vector_type(4))) float f4v;   // NT-capable float4
typedef const __attribute__((address_space(1))) void* gas_ptr;
typedef __attribute__((address_space(3))) void* las_ptr;

__device__ __forceinline__ unsigned short f2bf(float f) {
    __hip_bfloat16 h = __float2bfloat16(f);
    return __builtin_bit_cast(unsigned short, h);
}

// ---------------- Router: logits, noisy top-2, gates; fuses x -> bf16 ----------------
__global__ void router_kernel(const float* __restrict__ x,
                              const float* __restrict__ noise,
                              const float* __restrict__ Wr,
                              const float* __restrict__ br,
                              const float* __restrict__ Wn,
                              const float* __restrict__ bn,
                              __hip_bfloat16* __restrict__ xb,
                              int* __restrict__ tok_e,
                              float* __restrict__ tok_g)
{
    const int l = threadIdx.x & 63;
    const int w = threadIdx.x >> 6;
    const int t = blockIdx.x * 4 + w;
    const float* xr = x + (size_t)t * D_DIM;

    float ar[8] = {0,0,0,0,0,0,0,0};
    float an[8] = {0,0,0,0,0,0,0,0};
#pragma unroll
    for (int i = 0; i < 4; ++i) {
        int d = i * 256 + l * 4;
        f4v xv = __builtin_nontemporal_load((const f4v*)(xr + d));   // read-once stream
        ushort4 xq;
        xq.x = f2bf(xv.x); xq.y = f2bf(xv.y); xq.z = f2bf(xv.z); xq.w = f2bf(xv.w);
        *(ushort4*)(xb + (size_t)t * D_DIM + d) = xq;                // cached: re-read by gather
        float xs[4] = {xv.x, xv.y, xv.z, xv.w};
#pragma unroll
        for (int j = 0; j < 4; ++j) {
            const float* wrp = Wr + (size_t)(d + j) * 8;
            float4 wa = *(const float4*)wrp;
            float4 wb = *(const float4*)(wrp + 4);
            ar[0] = fmaf(xs[j], wa.x, ar[0]); ar[1] = fmaf(xs[j], wa.y, ar[1]);
            ar[2] = fmaf(xs[j], wa.z, ar[2]); ar[3] = fmaf(xs[j], wa.w, ar[3]);
            ar[4] = fmaf(xs[j], wb.x, ar[4]); ar[5] = fmaf(xs[j], wb.y, ar[5]);
            ar[6] = fmaf(xs[j], wb.z, ar[6]); ar[7] = fmaf(xs[j], wb.w, ar[7]);
            const float* wnp = Wn + (size_t)(d + j) * 8;
            float4 na = *(const float4*)wnp;
            float4 nb = *(const float4*)(wnp + 4);
            an[0] = fmaf(xs[j], na.x, an[0]); an[1] = fmaf(xs[j], na.y, an[1]);
            an[2] = fmaf(xs[j], na.z, an[2]); an[3] = fmaf(xs[j], na.w, an[3]);
            an[4] = fmaf(xs[j], nb.x, an[4]); an[5] = fmaf(xs[j], nb.y, an[5]);
            an[6] = fmaf(xs[j], nb.z, an[6]); an[7] = fmaf(xs[j], nb.w, an[7]);
        }
    }
#pragma unroll
    for (int e = 0; e < 8; ++e) {
#pragma unroll
        for (int s = 32; s > 0; s >>= 1) {
            ar[e] += __shfl_xor(ar[e], s, 64);
            an[e] += __shfl_xor(an[e], s, 64);
        }
    }
    if (l == 0) {
        float nv[8];
#pragma unroll
        for (int e = 0; e < 8; ++e) {
            float z = an[e] + bn[e];
            float sp = fmaxf(z, 0.f) + log1pf(expf(-fabsf(z)));   // softplus, stable
            nv[e] = ar[e] + br[e] + noise[(size_t)t * 8 + e] * sp;
        }
        int e0 = 0; float v0 = nv[0];
#pragma unroll
        for (int e = 1; e < 8; ++e) if (nv[e] > v0) { v0 = nv[e]; e0 = e; }  // ties -> lower idx
        int e1 = -1; float v1 = -3.4e38f;
#pragma unroll
        for (int e = 0; e < 8; ++e) if (e != e0 && nv[e] > v1) { v1 = nv[e]; e1 = e; }
        float ex = expf(v1 - v0);          // v1 <= v0, no overflow
        float p0 = 1.f / (1.f + ex);
        float p1 = ex * p0;
        tok_e[2 * t]     = e0; tok_e[2 * t + 1] = e1;
        tok_g[2 * t]     = p0; tok_g[2 * t + 1] = p1;
    }
}

// ---------- Capacity scan: wave e compacts its tokens in order; lb_loss sums ----------
__global__ void scan_kernel(const int* __restrict__ tok_e,
                            const float* __restrict__ tok_g,
                            int* __restrict__ routed,
                            int* __restrict__ inv,
                            int* __restrict__ nkept,
                            float* __restrict__ lb_out)
{
    const int e = threadIdx.x >> 6;
    const int l = threadIdx.x & 63;
    __shared__ float s_g[E_NUM];
    __shared__ int   s_c[E_NUM];

    int run = 0;
    float gsum = 0.f;
    for (int b = 0; b < 8; ++b) {
        int2  ev[16];
        float2 gv[16];
#pragma unroll
        for (int c = 0; c < 16; ++c) {
            int t = (b * 16 + c) * 64 + l;
            ev[c] = ((const int2*)tok_e)[t];
            gv[c] = ((const float2*)tok_g)[t];
        }
#pragma unroll
        for (int c = 0; c < 16; ++c) {
            int t = (b * 16 + c) * 64 + l;
            int j = (ev[c].x == e) ? 0 : ((ev[c].y == e) ? 1 : -1);
            bool sel = (j >= 0);
            unsigned long long m = __ballot(sel);
            if (sel) {
                int pos = run + __popcll(m & ((1ull << l) - 1ull));
                if (pos < CAPN) {
                    routed[e * CAP_PAD + pos] = t;
                    inv[2 * t + j] = e * CAP_PAD + pos;
                }
                gsum += (j == 0) ? gv[c].x : gv[c].y;   // pre-capacity, matches reference lb
            }
            run += __popcll(m);
        }
    }
#pragma unroll
    for (int s = 32; s > 0; s >>= 1) gsum += __shfl_xor(gsum, s, 64);
    int nk = min(run, CAPN);
    for (int s = nk + l; s < CAP_PAD; s += 64) routed[e * CAP_PAD + s] = 0;  // safe pad
    if (l == 0) { nkept[e] = nk; s_g[e] = gsum; s_c[e] = run; }
    __syncthreads();
    if (threadIdx.x == 0) {
        float lb = 0.f;
        for (int ee = 0; ee < E_NUM; ++ee)
            lb += (s_g[ee] / (float)T_TOK) * ((float)s_c[ee] / (float)T_TOK);
        lb_out[0] = lb * (float)E_NUM;
    }
}

// ---- Gather: xg[e][D/8][CAP_PAD][8] bf16 <- xb[routed[e][m]][dc*8..+8] ----
__global__ void gather_kernel(const ushort* __restrict__ xb,
                              const int* __restrict__ routed,
                              ushort* __restrict__ xg)
{
    const int dc = blockIdx.x & 127;
    const int e  = blockIdx.x >> 7;
    ushort* dst = xg + (size_t)(e * 128 + dc) * CAP_PAD * 8;
    const int* rte = routed + e * CAP_PAD;
#pragma unroll
    for (int p = 0; p < 9; ++p) {
        int m = p * 256 + threadIdx.x;
        int tok = rte[m];
        ulonglong2 v = *(const ulonglong2*)(xb + (size_t)tok * D_DIM + dc * 8);
        *(ulonglong2*)(dst + (size_t)m * 8) = v;   // cached: re-read by GEMM1
    }
}

// -- Weight chunking: W[e][K][N] f32 -> Wc[e][K/8][N][8] bf16 (k-chunked, n-contiguous) --
__global__ void chunk_weights(const float* __restrict__ in,
                              ushort* __restrict__ out,
                              int K, int N)
{
    __shared__ float tile[64][65];
    const int e = blockIdx.z;
    const int k0 = blockIdx.y * 64, n0 = blockIdx.x * 64;
    const float* src = in + (size_t)e * K * N;
    ushort* dst = out + (size_t)e * (K / 8) * N * 8;
    const int t = threadIdx.x;
    const int rr = t >> 4, c4 = (t & 15) * 4;
#pragma unroll
    for (int p = 0; p < 4; ++p) {
        int r = p * 16 + rr;
        f4v v = __builtin_nontemporal_load(
            (const f4v*)(src + (size_t)(k0 + r) * N + n0 + c4));   // read-once f32 stream
        tile[r][c4]     = v.x; tile[r][c4 + 1] = v.y;
        tile[r][c4 + 2] = v.z; tile[r][c4 + 3] = v.w;
    }
    __syncthreads();
    const int n = t & 63, kc = t >> 6;
#pragma unroll
    for (int p = 0; p < 2; ++p) {
        int kcc = p * 4 + kc;
        ushort g[8];
#pragma unroll
        for (int j = 0; j < 8; ++j) g[j] = f2bf(tile[kcc * 8 + j][n]);
        *(short8*)(dst + ((size_t)(k0 / 8 + kcc) * N + n0 + n) * 8) = *(const short8*)g;  // cached
    }
}

// ------ Expert GEMM: 256x128 block, 4 waves (2m x 2n), wave tile 128x64, BK=32 ------
// The r7/r10 structure was at the LDS-BW roofline (779 cyc/tile ~ 96KB rd + 48KB wr).
// Wave tile 64x64 -> 128x64 raises LDS arithmetic intensity 1.33x: per block-tile
// 48KB rd + 24KB wr for 128 MFMA (0.5625 KB/MFMA vs 0.75). 3 stages x 24KB = 72KB LDS,
// 2 blocks/CU. Counted vmcnt(6): 6 gloads/wave/tile (4A+2B), 2-deep prefetch, never
// drains in loop. Fragment ds_read_b128 keeps the 2-way-free bank pattern (0 conflicts).
template <int MODE>
__global__ __launch_bounds__(256, 2) void ffn_gemm(
    const ushort* __restrict__ A,     // [E][KD/8][CAP_PAD][8]
    const ushort* __restrict__ Bt,    // [E][KD/8][ND][8]
    const float* __restrict__ bias,
    const int* __restrict__ nkept,
    ushort* __restrict__ outH,
    float*  __restrict__ outP,
    int sshift, int nkt)
{
    constexpr int KD = (MODE == 1) ? D_DIM : H_DIM;
    constexpr int ND = (MODE == 1) ? H_DIM : D_DIM;
    constexpr int NC = KD / 8;
    __shared__ ushort lds[36864];   // 72 KiB = 3 stages x 24KB (A 16KB + B 8KB)

    // Plain XCD-aware swizzle (total blocks always % 8 == 0 here)
    unsigned total = gridDim.x * gridDim.y * gridDim.z;
    unsigned flat  = blockIdx.x + gridDim.x * (blockIdx.y + gridDim.y * blockIdx.z);
    unsigned sw    = (flat & 7) * (total >> 3) + (flat >> 3);
    unsigned bn    = sw % gridDim.x;
    unsigned t1    = sw / gridDim.x;
    unsigned bm    = t1 % gridDim.y;
    unsigned bz    = t1 / gridDim.y;

    const int e  = (int)(bz >> sshift);
    const int sp = (int)(bz & ((1u << sshift) - 1u));
    const int m0 = (int)bm * 256, n0 = (int)bn * 128;
    if (m0 >= nkept[e]) return;
    const int kc0 = sp * (nkt << 2);   // first k-chunk of this split (4 chunks / K-tile)

    const int tid  = threadIdx.x;
    const int lane = tid & 63;
    const int w    = tid >> 6;           // 0..3
    const int aw   = w << 10;            // A LDS wave base (bytes): rows w*64..
    const int bci  = tid >> 7;           // B chunk sub-selector (0|1), wave-uniform
    const int bw   = (w & 1) << 10;      // B LDS row-half base (bytes)

    const size_t sAc = (size_t)CAP_PAD * 8;   // chunk stride (ushorts)
    const size_t sBc = (size_t)ND * 8;
    const size_t tsA = 4 * sAc;               // K-tile stride (ushorts)
    const size_t tsB = 4 * sBc;

    // Staging bases: A row = m0 + tid (256 rows); B row = n0 + (tid&127), chunk +bci
    const ushort* Ae = A  + ((size_t)e * NC * CAP_PAD + (size_t)(m0 + tid)) * 8
                          + (size_t)kc0 * sAc;
    const ushort* Be = Bt + ((size_t)e * NC * ND + (size_t)(n0 + (tid & 127))) * 8
                          + (size_t)(kc0 + bci) * sBc;

    auto gl = [&](const ushort* g, int ldsbyte) {
        __builtin_amdgcn_global_load_lds((gas_ptr)g, (las_ptr)((char*)lds + ldsbyte), 16, 0, 0);
    };
    auto issueA = [&](size_t off, int stB) {   // 4 issues: chunk c, all 256 rows
        gl(Ae + off,            stB + 0 * 4096 + aw);
        gl(Ae + off + sAc,      stB + 1 * 4096 + aw);
        gl(Ae + off + 2 * sAc,  stB + 2 * 4096 + aw);
        gl(Ae + off + 3 * sAc,  stB + 3 * 4096 + aw);
    };
    auto issueB = [&](size_t off, int stB) {   // 2 issues: chunks {2j+bci}, 128 rows
        gl(Be + off,            stB + 16384 + (0 + bci) * 2048 + bw);
        gl(Be + off + 2 * sBc,  stB + 16384 + (2 + bci) * 2048 + bw);
    };

    // Prologue: tiles 0,1 -> stages 0,1. vmcnt(6) => tile 0 resident, tile 1 in flight.
    issueA(0, 0);        issueB(0, 0);
    issueA(tsA, 24576);  issueB(tsB, 24576);
    asm volatile("s_waitcnt vmcnt(6)" ::: "memory");
    __builtin_amdgcn_s_barrier();

    f32x4 acc[8][4] = {};
    const int wm = (w >> 1) * 128;       // wave row base within block tile
    const int wn = (w & 1) * 64;         // wave col base
    const int fr = lane & 15;
    const int fq = lane >> 4;

    int rdS = 0;              // ushort index of read stage (stride 12288 = 24KB)
    int wrB = 49152;          // byte offset of write stage ((kt+2)%3)
    size_t oA = 2 * tsA;      // prefetch offset for tile kt+2 (clamped via cond. advance)
    size_t oB = 2 * tsB;

    for (int kt = 0; kt < nkt; ++kt) {
        const ushort* Ard = lds + rdS;           // A region: [4 ch][256 r][8]
        const ushort* Brd = lds + rdS + 8192;    // B region: [4 ch][128 r][8] (+16KB)

        short8 af[8], bfr[4];
#pragma unroll
        for (int j = 0; j < 4; ++j)
            bfr[j] = *(const short8*)(Brd + fq * 1024 + (wn + j * 16 + fr) * 8);
#pragma unroll
        for (int i = 0; i < 8; ++i)
            af[i] = *(const short8*)(Ard + fq * 2048 + (wm + i * 16 + fr) * 8);

        issueA(oA, wrB);
        issueB(oB, wrB);

        __builtin_amdgcn_s_setprio(1);
#pragma unroll
        for (int i = 0; i < 8; ++i)
#pragma unroll
            for (int j = 0; j < 4; ++j)
                acc[i][j] = __builtin_amdgcn_mfma_f32_16x16x32_bf16(af[i], bfr[j], acc[i][j], 0, 0, 0);
        __builtin_amdgcn_s_setprio(0);

        asm volatile("s_waitcnt vmcnt(6)" ::: "memory");   // K-tile kt+1 resident
        __builtin_amdgcn_s_barrier();

        rdS = (rdS == 24576) ? 0 : rdS + 12288;
        wrB = (wrB == 49152) ? 0 : wrB + 24576;
        if (kt < nkt - 3) { oA += tsA; oB += tsB; }   // clamp: last tiles re-stage nkt-1
    }

    // ---- epilogue (cached stores) ----
#pragma unroll
    for (int j = 0; j < 4; ++j) {
        int nc = n0 + wn + j * 16 + fr;
        float bv = (MODE == 1) ? bias[e * ND + nc] : 0.f;
#pragma unroll
        for (int i = 0; i < 8; ++i) {
            int mr = m0 + wm + i * 16 + (fq << 2);
#pragma unroll
            for (int r = 0; r < 4; ++r) {
                float v = acc[i][j][r] + bv;
                if (MODE == 1) {
                    v = fmaxf(v, 0.f);
                    // hbuf chunked: [e][H/8][CAP_PAD][8]
                    outH[(((size_t)e * 512 + (nc >> 3)) * CAP_PAD + mr + r) * 8 + (nc & 7)] = f2bf(v);
                } else {
                    outP[((size_t)(sp * E_NUM + e) * CAP_PAD + mr + r) * D_DIM + nc] = v;
                }
            }
        }
    }
}

// -------- Final combine: out[t] = sum_j gate_j * (sum_s part[s][inv_j] + b2[e_j]) --------
__global__ void combine_kernel(const float* __restrict__ part,
                               const int* __restrict__ inv,
                               const float* __restrict__ tok_g,
                               const float* __restrict__ b2,
                               int S,
                               float* __restrict__ out)
{
    const int t = blockIdx.x;
    const int d = threadIdx.x * 4;
    f4v r = {0.f, 0.f, 0.f, 0.f};
#pragma unroll
    for (int j = 0; j < 2; ++j) {
        int i = inv[2 * t + j];
        if (i >= 0) {
            float g = tok_g[2 * t + j];
            int e = i / CAP_PAD;
            f4v a = *(const f4v*)(b2 + (size_t)e * D_DIM + d);
            for (int s = 0; s < S; ++s) {
                f4v p = __builtin_nontemporal_load(
                    (const f4v*)(part + ((size_t)s * E_NUM * CAP_PAD + i) * D_DIM + d));
                a += p;
            }
            r += g * a;
        }
    }
    __builtin_nontemporal_store(r, (f4v*)(out + (size_t)t * D_DIM + d));
}

extern "C" void kernel_launch(void* const* d_in, const int* in_sizes, int n_in,
                              void* d_out, int out_size, void* d_ws, size_t ws_size,
                              hipStream_t stream)
{
    const float* x  = (const float*)d_in[0];
    const float* nz = (const float*)d_in[1];
    const float* Wr = (const float*)d_in[2];
    const float* br = (const float*)d_in[3];
    const float* Wn = (const float*)d_in[4];
    const float* bn = (const float*)d_in[5];
    const float* W1 = (const float*)d_in[6];
    const float* b1 = (const float*)d_in[7];
    const float* W2 = (const float*)d_in[8];
    const float* b2 = (const float*)d_in[9];
    float* out = (float*)d_out;
    char* ws = (char*)d_ws;

    // Workspace: [w2c 64MB][hbuf 144MB][small 1MB][dyn]
    //   dyn phase1: xg(36MB) + xb(16MB) + w1c(64MB)   (all dead after GEMM1)
    //   dyn phase2: part (S * 75.5MB)                 (overlays phase1)
    const size_t sz_w2c = (size_t)E_NUM * (H_DIM / 8) * D_DIM * 8 * 2;   // 67,108,864
    const size_t sz_h   = (size_t)E_NUM * 512 * CAP_PAD * 8 * 2;         // 150,994,944
    const size_t o_w2c  = 0;
    const size_t o_h    = o_w2c + sz_w2c;
    const size_t o_sm   = o_h + sz_h;
    const size_t o_dyn  = o_sm + (1u << 20);
    const size_t sz_xg  = (size_t)E_NUM * 128 * CAP_PAD * 8 * 2;         // 37,748,736
    const size_t sz_xb  = (size_t)T_TOK * D_DIM * 2;                     // 16,777,216
    const size_t sz_w1c = (size_t)E_NUM * (D_DIM / 8) * H_DIM * 8 * 2;   // 67,108,864
    const size_t sz_p1  = sz_xg + sz_xb + sz_w1c;                        // 121,634,816
    const size_t sz_part1 = (size_t)E_NUM * CAP_PAD * D_DIM * 4;         // 75,497,472

    int sshift = 1;
    while (sshift > 0) {
        size_t need = o_dyn + ((sz_part1 << sshift) > sz_p1 ? (sz_part1 << sshift) : sz_p1);
        if (need <= ws_size) break;
        --sshift;
    }
    const int S = 1 << sshift;

    ushort* w2c  = (ushort*)(ws + o_w2c);
    ushort* hbuf = (ushort*)(ws + o_h);
    int*    rt   = (int*)(ws + o_sm);
    int*    te   = (int*)(ws + o_sm + 131072);
    float*  tg   = (float*)(ws + o_sm + 262144);
    int*    inv  = (int*)(ws + o_sm + 393216);
    int*    nk   = (int*)(ws + o_sm + 524288);
    ushort* xg   = (ushort*)(ws + o_dyn);
    ushort* xb   = (ushort*)(ws + o_dyn + sz_xg);
    ushort* w1c  = (ushort*)(ws + o_dyn + sz_xg + sz_xb);
    float*  part = (float*)(ws + o_dyn);   // overlays xg/xb/w1c (dead after GEMM1)

    (void)hipMemsetAsync(inv, 0xFF, (size_t)T_TOK * 2 * 4, stream);   // inv = -1

    router_kernel<<<T_TOK / 4, 256, 0, stream>>>(x, nz, Wr, br, Wn, bn,
                                                 (__hip_bfloat16*)xb, te, tg);
    scan_kernel<<<1, 512, 0, stream>>>(te, tg, rt, inv, nk, out + (size_t)T_TOK * D_DIM);
    // W2 first so w1c is freshest in L3 when GEMM1 runs.
    chunk_weights<<<dim3(D_DIM / 64, H_DIM / 64, E_NUM), 256, 0, stream>>>(W2, w2c, H_DIM, D_DIM);
    chunk_weights<<<dim3(H_DIM / 64, D_DIM / 64, E_NUM), 256, 0, stream>>>(W1, w1c, D_DIM, H_DIM);
    gather_kernel<<<E_NUM * 128, 256, 0, stream>>>(xb, rt, xg);

    // GEMM1: per expert [2304 x 1024] @ [1024 x 4096] -> hbuf chunked (bf16, relu+b1)
    // Grid 32 x 9 x 8 = 2304 blocks (256m x 128n tiles).
    ffn_gemm<1><<<dim3(H_DIM / 128, MT, E_NUM), 256, 0, stream>>>(
        xg, w1c, b1, nk, hbuf, nullptr, 0, D_DIM / 32);

    // GEMM2: per expert [2304 x 4096] @ [4096 x 1024], split-K=S -> f32 partials
    // Grid 8 x 9 x 16 = 1152 blocks.
    ffn_gemm<2><<<dim3(D_DIM / 128, MT, E_NUM << sshift), 256, 0, stream>>>(
        hbuf, w2c, nullptr, nk, nullptr, part, sshift, (H_DIM / 32) >> sshift);

    combine_kernel<<<T_TOK, 256, 0, stream>>>(part, inv, tg, b2, S, out);
}

// Round 13
// 531.950 us; speedup vs baseline: 1.0994x; 1.0617x over previous
//
#include <hip/hip_runtime.h>
#include <hip/hip_bf16.h>

#define D_DIM 1024
#define H_DIM 4096
#define E_NUM 8
#define T_TOK 8192
#define CAPN 2252
#define CAP_PAD 2304   // 9 * 256
#define MT 9
#define NG1 2304       // GEMM1 blocks: 32 * 9 * 8

typedef __attribute__((ext_vector_type(8))) short short8;
typedef __attribute__((ext_vector_type(4))) float f32x4;
typedef __attribute__((ext_vector_type(4))) float f4v;
typedef __attribute__((ext_vector_type(4))) ushort u16x4;
typedef const __attribute__((address_space(1))) void* gas_ptr;
typedef __attribute__((address_space(3))) void* las_ptr;

__device__ __forceinline__ unsigned short f2bf(float f) {
    __hip_bfloat16 h = __float2bfloat16(f);
    return __builtin_bit_cast(unsigned short, h);
}
__device__ __forceinline__ float bfu2f(ushort u) {
    unsigned v = (unsigned)u << 16;
    return __builtin_bit_cast(float, v);
}

// ---------------- Router: logits, noisy top-2, gates; fuses x -> bf16 ----------------
__global__ void router_kernel(const float* __restrict__ x,
                              const float* __restrict__ noise,
                              const float* __restrict__ Wr,
                              const float* __restrict__ br,
                              const float* __restrict__ Wn,
                              const float* __restrict__ bn,
                              __hip_bfloat16* __restrict__ xb,
                              int* __restrict__ tok_e,
                              float* __restrict__ tok_g)
{
    const int l = threadIdx.x & 63;
    const int w = threadIdx.x >> 6;
    const int t = blockIdx.x * 4 + w;
    const float* xr = x + (size_t)t * D_DIM;

    float ar[8] = {0,0,0,0,0,0,0,0};
    float an[8] = {0,0,0,0,0,0,0,0};
#pragma unroll
    for (int i = 0; i < 4; ++i) {
        int d = i * 256 + l * 4;
        f4v xv = __builtin_nontemporal_load((const f4v*)(xr + d));   // read-once stream
        ushort4 xq;
        xq.x = f2bf(xv.x); xq.y = f2bf(xv.y); xq.z = f2bf(xv.z); xq.w = f2bf(xv.w);
        *(ushort4*)(xb + (size_t)t * D_DIM + d) = xq;                // cached: re-read by gather
        float xs[4] = {xv.x, xv.y, xv.z, xv.w};
#pragma unroll
        for (int j = 0; j < 4; ++j) {
            const float* wrp = Wr + (size_t)(d + j) * 8;
            float4 wa = *(const float4*)wrp;
            float4 wb = *(const float4*)(wrp + 4);
            ar[0] = fmaf(xs[j], wa.x, ar[0]); ar[1] = fmaf(xs[j], wa.y, ar[1]);
            ar[2] = fmaf(xs[j], wa.z, ar[2]); ar[3] = fmaf(xs[j], wa.w, ar[3]);
            ar[4] = fmaf(xs[j], wb.x, ar[4]); ar[5] = fmaf(xs[j], wb.y, ar[5]);
            ar[6] = fmaf(xs[j], wb.z, ar[6]); ar[7] = fmaf(xs[j], wb.w, ar[7]);
            const float* wnp = Wn + (size_t)(d + j) * 8;
            float4 na = *(const float4*)wnp;
            float4 nb = *(const float4*)(wnp + 4);
            an[0] = fmaf(xs[j], na.x, an[0]); an[1] = fmaf(xs[j], na.y, an[1]);
            an[2] = fmaf(xs[j], na.z, an[2]); an[3] = fmaf(xs[j], na.w, an[3]);
            an[4] = fmaf(xs[j], nb.x, an[4]); an[5] = fmaf(xs[j], nb.y, an[5]);
            an[6] = fmaf(xs[j], nb.z, an[6]); an[7] = fmaf(xs[j], nb.w, an[7]);
        }
    }
#pragma unroll
    for (int e = 0; e < 8; ++e) {
#pragma unroll
        for (int s = 32; s > 0; s >>= 1) {
            ar[e] += __shfl_xor(ar[e], s, 64);
            an[e] += __shfl_xor(an[e], s, 64);
        }
    }
    if (l == 0) {
        float nv[8];
#pragma unroll
        for (int e = 0; e < 8; ++e) {
            float z = an[e] + bn[e];
            float sp = fmaxf(z, 0.f) + log1pf(expf(-fabsf(z)));   // softplus, stable
            nv[e] = ar[e] + br[e] + noise[(size_t)t * 8 + e] * sp;
        }
        int e0 = 0; float v0 = nv[0];
#pragma unroll
        for (int e = 1; e < 8; ++e) if (nv[e] > v0) { v0 = nv[e]; e0 = e; }  // ties -> lower idx
        int e1 = -1; float v1 = -3.4e38f;
#pragma unroll
        for (int e = 0; e < 8; ++e) if (e != e0 && nv[e] > v1) { v1 = nv[e]; e1 = e; }
        float ex = expf(v1 - v0);          // v1 <= v0, no overflow
        float p0 = 1.f / (1.f + ex);
        float p1 = ex * p0;
        tok_e[2 * t]     = e0; tok_e[2 * t + 1] = e1;
        tok_g[2 * t]     = p0; tok_g[2 * t + 1] = p1;
    }
}

// ---------- Capacity scan: wave e compacts its tokens in order; lb_loss sums ----------
__global__ void scan_kernel(const int* __restrict__ tok_e,
                            const float* __restrict__ tok_g,
                            int* __restrict__ routed,
                            int* __restrict__ inv,
                            int* __restrict__ nkept,
                            float* __restrict__ lb_out)
{
    const int e = threadIdx.x >> 6;
    const int l = threadIdx.x & 63;
    __shared__ float s_g[E_NUM];
    __shared__ int   s_c[E_NUM];

    int run = 0;
    float gsum = 0.f;
    for (int b = 0; b < 8; ++b) {
        int2  ev[16];
        float2 gv[16];
#pragma unroll
        for (int c = 0; c < 16; ++c) {
            int t = (b * 16 + c) * 64 + l;
            ev[c] = ((const int2*)tok_e)[t];
            gv[c] = ((const float2*)tok_g)[t];
        }
#pragma unroll
        for (int c = 0; c < 16; ++c) {
            int t = (b * 16 + c) * 64 + l;
            int j = (ev[c].x == e) ? 0 : ((ev[c].y == e) ? 1 : -1);
            bool sel = (j >= 0);
            unsigned long long m = __ballot(sel);
            if (sel) {
                int pos = run + __popcll(m & ((1ull << l) - 1ull));
                if (pos < CAPN) {
                    routed[e * CAP_PAD + pos] = t;
                    inv[2 * t + j] = e * CAP_PAD + pos;
                }
                gsum += (j == 0) ? gv[c].x : gv[c].y;   // pre-capacity, matches reference lb
            }
            run += __popcll(m);
        }
    }
#pragma unroll
    for (int s = 32; s > 0; s >>= 1) gsum += __shfl_xor(gsum, s, 64);
    int nk = min(run, CAPN);
    for (int s = nk + l; s < CAP_PAD; s += 64) routed[e * CAP_PAD + s] = 0;  // safe pad
    if (l == 0) { nkept[e] = nk; s_g[e] = gsum; s_c[e] = run; }
    __syncthreads();
    if (threadIdx.x == 0) {
        float lb = 0.f;
        for (int ee = 0; ee < E_NUM; ++ee)
            lb += (s_g[ee] / (float)T_TOK) * ((float)s_c[ee] / (float)T_TOK);
        lb_out[0] = lb * (float)E_NUM;
    }
}

// ---- Gather: xg[e][D/8][CAP_PAD][8] bf16 <- xb[routed[e][m]][dc*8..+8] ----
__global__ void gather_kernel(const ushort* __restrict__ xb,
                              const int* __restrict__ routed,
                              ushort* __restrict__ xg)
{
    const int dc = blockIdx.x & 127;
    const int e  = blockIdx.x >> 7;
    ushort* dst = xg + (size_t)(e * 128 + dc) * CAP_PAD * 8;
    const int* rte = routed + e * CAP_PAD;
#pragma unroll
    for (int p = 0; p < 9; ++p) {
        int m = p * 256 + threadIdx.x;
        int tok = rte[m];
        ulonglong2 v = *(const ulonglong2*)(xb + (size_t)tok * D_DIM + dc * 8);
        *(ulonglong2*)(dst + (size_t)m * 8) = v;   // cached: re-read by GEMM1
    }
}

// -- Weight chunk body: W[e][K][N] f32 -> Wc[e][K/8][N][8] bf16 --
__device__ __forceinline__ void chunk_body(const float* __restrict__ src0,
                                           ushort* __restrict__ dstb,
                                           int K, int N, unsigned i,
                                           float (*tile)[65])
{
    const int nx = N >> 6;
    const int bx = i % nx;
    const unsigned rem = i / nx;
    const int by = rem % (K >> 6);
    const int e  = rem / (K >> 6);
    const int k0 = by * 64, n0 = bx * 64;
    const float* src = src0 + (size_t)e * K * N;
    ushort* dst = dstb + (size_t)e * (K / 8) * N * 8;
    const int t = threadIdx.x;
    const int rr = t >> 4, c4 = (t & 15) * 4;
#pragma unroll
    for (int p = 0; p < 4; ++p) {
        int r = p * 16 + rr;
        f4v v = __builtin_nontemporal_load(
            (const f4v*)(src + (size_t)(k0 + r) * N + n0 + c4));   // read-once f32 stream
        tile[r][c4]     = v.x; tile[r][c4 + 1] = v.y;
        tile[r][c4 + 2] = v.z; tile[r][c4 + 3] = v.w;
    }
    __syncthreads();
    const int n = t & 63, kc = t >> 6;
#pragma unroll
    for (int p = 0; p < 2; ++p) {
        int kcc = p * 4 + kc;
        ushort g[8];
#pragma unroll
        for (int j = 0; j < 8; ++j) g[j] = f2bf(tile[kcc * 8 + j][n]);
        *(short8*)(dst + ((size_t)(k0 / 8 + kcc) * N + n0 + n) * 8) = *(const short8*)g;
    }
}

__global__ void chunk_weights(const float* __restrict__ in,
                              ushort* __restrict__ out, int K, int N)
{
    __shared__ float tile[64][65];
    chunk_body(in, out, K, N, blockIdx.x, tile);
}

// ------ GEMM1 (256x128 block, wave 128x64, BK=32, 3-stage) fused with chunkW2 ------
// Blocks [0, NG1): GEMM1  h = relu(xg @ W1c + b1) -> hbuf chunked bf16.
// Blocks [NG1, NG1+8192): chunk W2 f32->bf16 (backfills CUs / idle HBM BW while
// GEMM1 runs; GEMM2 needs both anyway). GEMM structure identical to r12.
__global__ __launch_bounds__(256, 2) void gemm1_chunk2(
    const ushort* __restrict__ A,     // xg [E][128][CAP_PAD][8]
    const ushort* __restrict__ Bt,    // w1c [E][128][H][8]
    const float* __restrict__ bias,
    const int* __restrict__ nkept,
    ushort* __restrict__ outH,
    const float* __restrict__ W2,
    ushort* __restrict__ w2c)
{
    __shared__ ushort lds[36864];   // 72 KiB (GEMM); chunk aliases 16.6 KiB of it
    const unsigned blk = blockIdx.x;

    if (blk >= NG1) {
        chunk_body(W2, w2c, H_DIM, D_DIM, blk - NG1, (float(*)[65])lds);
        return;
    }

    constexpr int ND = H_DIM;
    constexpr int NC = D_DIM / 8;
    constexpr int nkt = D_DIM / 32;

    // XCD swizzle within the GEMM sub-grid (NG1 % 8 == 0)
    unsigned sw = (blk & 7) * (NG1 >> 3) + (blk >> 3);
    unsigned bn = sw % (H_DIM / 128);
    unsigned t1 = sw / (H_DIM / 128);
    unsigned bm = t1 % MT;
    unsigned e  = t1 / MT;

    const int m0 = (int)bm * 256, n0 = (int)bn * 128;
    if (m0 >= nkept[e]) return;

    const int tid  = threadIdx.x;
    const int lane = tid & 63;
    const int w    = tid >> 6;
    const int aw   = w << 10;
    const int bci  = tid >> 7;
    const int bw   = (w & 1) << 10;

    const size_t sAc = (size_t)CAP_PAD * 8;
    const size_t sBc = (size_t)ND * 8;
    const size_t tsA = 4 * sAc;
    const size_t tsB = 4 * sBc;

    const ushort* Ae = A  + ((size_t)e * NC * CAP_PAD + (size_t)(m0 + tid)) * 8;
    const ushort* Be = Bt + ((size_t)e * NC * ND + (size_t)(n0 + (tid & 127))) * 8
                          + (size_t)bci * sBc;

    auto gl = [&](const ushort* g, int ldsbyte) {
        __builtin_amdgcn_global_load_lds((gas_ptr)g, (las_ptr)((char*)lds + ldsbyte), 16, 0, 0);
    };
    auto issueA = [&](size_t off, int stB) {
        gl(Ae + off,           stB + 0 * 4096 + aw);
        gl(Ae + off + sAc,     stB + 1 * 4096 + aw);
        gl(Ae + off + 2 * sAc, stB + 2 * 4096 + aw);
        gl(Ae + off + 3 * sAc, stB + 3 * 4096 + aw);
    };
    auto issueB = [&](size_t off, int stB) {
        gl(Be + off,           stB + 16384 + (0 + bci) * 2048 + bw);
        gl(Be + off + 2 * sBc, stB + 16384 + (2 + bci) * 2048 + bw);
    };

    issueA(0, 0);        issueB(0, 0);
    issueA(tsA, 24576);  issueB(tsB, 24576);
    asm volatile("s_waitcnt vmcnt(6)" ::: "memory");
    __builtin_amdgcn_s_barrier();

    f32x4 acc[8][4] = {};
    const int wm = (w >> 1) * 128;
    const int wn = (w & 1) * 64;
    const int fr = lane & 15;
    const int fq = lane >> 4;

    int rdS = 0;
    int wrB = 49152;
    size_t oA = 2 * tsA;
    size_t oB = 2 * tsB;

    for (int kt = 0; kt < nkt; ++kt) {
        const ushort* Ard = lds + rdS;
        const ushort* Brd = lds + rdS + 8192;

        short8 af[8], bfr[4];
#pragma unroll
        for (int j = 0; j < 4; ++j)
            bfr[j] = *(const short8*)(Brd + fq * 1024 + (wn + j * 16 + fr) * 8);
#pragma unroll
        for (int i = 0; i < 8; ++i)
            af[i] = *(const short8*)(Ard + fq * 2048 + (wm + i * 16 + fr) * 8);

        issueA(oA, wrB);
        issueB(oB, wrB);

        __builtin_amdgcn_s_setprio(1);
#pragma unroll
        for (int i = 0; i < 8; ++i)
#pragma unroll
            for (int j = 0; j < 4; ++j)
                acc[i][j] = __builtin_amdgcn_mfma_f32_16x16x32_bf16(af[i], bfr[j], acc[i][j], 0, 0, 0);
        __builtin_amdgcn_s_setprio(0);

        asm volatile("s_waitcnt vmcnt(6)" ::: "memory");
        __builtin_amdgcn_s_barrier();

        rdS = (rdS == 24576) ? 0 : rdS + 12288;
        wrB = (wrB == 49152) ? 0 : wrB + 24576;
        if (kt < nkt - 3) { oA += tsA; oB += tsB; }
    }

#pragma unroll
    for (int j = 0; j < 4; ++j) {
        int nc = n0 + wn + j * 16 + fr;
        float bv = bias[e * ND + nc];
#pragma unroll
        for (int i = 0; i < 8; ++i) {
            int mr = m0 + wm + i * 16 + (fq << 2);
#pragma unroll
            for (int r = 0; r < 4; ++r) {
                float v = fmaxf(acc[i][j][r] + bv, 0.f);
                outH[(((size_t)e * 512 + (nc >> 3)) * CAP_PAD + mr + r) * 8 + (nc & 7)] = f2bf(v);
            }
        }
    }
}

// ------ GEMM2: 256x128 block, wave 128x64, BK=32, 3-stage; bf16 split-K partials ------
__global__ __launch_bounds__(256, 2) void ffn_gemm2(
    const ushort* __restrict__ A,     // hbuf [E][512][CAP_PAD][8]
    const ushort* __restrict__ Bt,    // w2c [E][512][D][8]
    const int* __restrict__ nkept,
    ushort* __restrict__ outP,        // bf16 partials [S][E][CAP_PAD][D]
    int sshift, int nkt)
{
    constexpr int KD = H_DIM;
    constexpr int ND = D_DIM;
    constexpr int NC = KD / 8;
    __shared__ ushort lds[36864];

    unsigned total = gridDim.x * gridDim.y * gridDim.z;
    unsigned flat  = blockIdx.x + gridDim.x * (blockIdx.y + gridDim.y * blockIdx.z);
    unsigned sw    = (flat & 7) * (total >> 3) + (flat >> 3);
    unsigned bn    = sw % gridDim.x;
    unsigned t1    = sw / gridDim.x;
    unsigned bm    = t1 % gridDim.y;
    unsigned bz    = t1 / gridDim.y;

    const int e  = (int)(bz >> sshift);
    const int sp = (int)(bz & ((1u << sshift) - 1u));
    const int m0 = (int)bm * 256, n0 = (int)bn * 128;
    if (m0 >= nkept[e]) return;
    const int kc0 = sp * (nkt << 2);

    const int tid  = threadIdx.x;
    const int lane = tid & 63;
    const int w    = tid >> 6;
    const int aw   = w << 10;
    const int bci  = tid >> 7;
    const int bw   = (w & 1) << 10;

    const size_t sAc = (size_t)CAP_PAD * 8;
    const size_t sBc = (size_t)ND * 8;
    const size_t tsA = 4 * sAc;
    const size_t tsB = 4 * sBc;

    const ushort* Ae = A  + ((size_t)e * NC * CAP_PAD + (size_t)(m0 + tid)) * 8
                          + (size_t)kc0 * sAc;
    const ushort* Be = Bt + ((size_t)e * NC * ND + (size_t)(n0 + (tid & 127))) * 8
                          + (size_t)(kc0 + bci) * sBc;

    auto gl = [&](const ushort* g, int ldsbyte) {
        __builtin_amdgcn_global_load_lds((gas_ptr)g, (las_ptr)((char*)lds + ldsbyte), 16, 0, 0);
    };
    auto issueA = [&](size_t off, int stB) {
        gl(Ae + off,           stB + 0 * 4096 + aw);
        gl(Ae + off + sAc,     stB + 1 * 4096 + aw);
        gl(Ae + off + 2 * sAc, stB + 2 * 4096 + aw);
        gl(Ae + off + 3 * sAc, stB + 3 * 4096 + aw);
    };
    auto issueB = [&](size_t off, int stB) {
        gl(Be + off,           stB + 16384 + (0 + bci) * 2048 + bw);
        gl(Be + off + 2 * sBc, stB + 16384 + (2 + bci) * 2048 + bw);
    };

    issueA(0, 0);        issueB(0, 0);
    issueA(tsA, 24576);  issueB(tsB, 24576);
    asm volatile("s_waitcnt vmcnt(6)" ::: "memory");
    __builtin_amdgcn_s_barrier();

    f32x4 acc[8][4] = {};
    const int wm = (w >> 1) * 128;
    const int wn = (w & 1) * 64;
    const int fr = lane & 15;
    const int fq = lane >> 4;

    int rdS = 0;
    int wrB = 49152;
    size_t oA = 2 * tsA;
    size_t oB = 2 * tsB;

    for (int kt = 0; kt < nkt; ++kt) {
        const ushort* Ard = lds + rdS;
        const ushort* Brd = lds + rdS + 8192;

        short8 af[8], bfr[4];
#pragma unroll
        for (int j = 0; j < 4; ++j)
            bfr[j] = *(const short8*)(Brd + fq * 1024 + (wn + j * 16 + fr) * 8);
#pragma unroll
        for (int i = 0; i < 8; ++i)
            af[i] = *(const short8*)(Ard + fq * 2048 + (wm + i * 16 + fr) * 8);

        issueA(oA, wrB);
        issueB(oB, wrB);

        __builtin_amdgcn_s_setprio(1);
#pragma unroll
        for (int i = 0; i < 8; ++i)
#pragma unroll
            for (int j = 0; j < 4; ++j)
                acc[i][j] = __builtin_amdgcn_mfma_f32_16x16x32_bf16(af[i], bfr[j], acc[i][j], 0, 0, 0);
        __builtin_amdgcn_s_setprio(0);

        asm volatile("s_waitcnt vmcnt(6)" ::: "memory");
        __builtin_amdgcn_s_barrier();

        rdS = (rdS == 24576) ? 0 : rdS + 12288;
        wrB = (wrB == 49152) ? 0 : wrB + 24576;
        if (kt < nkt - 3) { oA += tsA; oB += tsB; }
    }

#pragma unroll
    for (int j = 0; j < 4; ++j) {
        int nc = n0 + wn + j * 16 + fr;
#pragma unroll
        for (int i = 0; i < 8; ++i) {
            int mr = m0 + wm + i * 16 + (fq << 2);
#pragma unroll
            for (int r = 0; r < 4; ++r)
                outP[((size_t)(sp * E_NUM + e) * CAP_PAD + mr + r) * D_DIM + nc] =
                    f2bf(acc[i][j][r]);
        }
    }
}

// -------- Final combine: out[t] = sum_j gate_j * (sum_s part[s][inv_j] + b2[e_j]) --------
__global__ void combine_kernel(const ushort* __restrict__ part,
                               const int* __restrict__ inv,
                               const float* __restrict__ tok_g,
                               const float* __restrict__ b2,
                               int S,
                               float* __restrict__ out)
{
    const int t = blockIdx.x;
    const int d = threadIdx.x * 4;
    f4v r = {0.f, 0.f, 0.f, 0.f};
#pragma unroll
    for (int j = 0; j < 2; ++j) {
        int i = inv[2 * t + j];
        if (i >= 0) {
            float g = tok_g[2 * t + j];
            int e = i / CAP_PAD;
            f4v a = *(const f4v*)(b2 + (size_t)e * D_DIM + d);
            for (int s = 0; s < S; ++s) {
                u16x4 p = __builtin_nontemporal_load(
                    (const u16x4*)(part + ((size_t)s * E_NUM * CAP_PAD + i) * D_DIM + d));
                a.x += bfu2f(p.x); a.y += bfu2f(p.y);
                a.z += bfu2f(p.z); a.w += bfu2f(p.w);
            }
            r += g * a;
        }
    }
    __builtin_nontemporal_store(r, (f4v*)(out + (size_t)t * D_DIM + d));
}

extern "C" void kernel_launch(void* const* d_in, const int* in_sizes, int n_in,
                              void* d_out, int out_size, void* d_ws, size_t ws_size,
                              hipStream_t stream)
{
    const float* x  = (const float*)d_in[0];
    const float* nz = (const float*)d_in[1];
    const float* Wr = (const float*)d_in[2];
    const float* br = (const float*)d_in[3];
    const float* Wn = (const float*)d_in[4];
    const float* bn = (const float*)d_in[5];
    const float* W1 = (const float*)d_in[6];
    const float* b1 = (const float*)d_in[7];
    const float* W2 = (const float*)d_in[8];
    const float* b2 = (const float*)d_in[9];
    float* out = (float*)d_out;
    char* ws = (char*)d_ws;

    // Workspace: [w2c 64MB][hbuf 144MB][small 1MB][dyn]
    //   dyn phase1: xg(36MB) + xb(16MB) + w1c(64MB)   (all dead after GEMM1)
    //   dyn phase2: part bf16 (S * 37.7MB)            (overlays phase1)
    const size_t sz_w2c = (size_t)E_NUM * (H_DIM / 8) * D_DIM * 8 * 2;   // 67,108,864
    const size_t sz_h   = (size_t)E_NUM * 512 * CAP_PAD * 8 * 2;         // 150,994,944
    const size_t o_w2c  = 0;
    const size_t o_h    = o_w2c + sz_w2c;
    const size_t o_sm   = o_h + sz_h;
    const size_t o_dyn  = o_sm + (1u << 20);
    const size_t sz_xg  = (size_t)E_NUM * 128 * CAP_PAD * 8 * 2;         // 37,748,736
    const size_t sz_xb  = (size_t)T_TOK * D_DIM * 2;                     // 16,777,216
    const size_t sz_w1c = (size_t)E_NUM * (D_DIM / 8) * H_DIM * 8 * 2;   // 67,108,864
    const size_t sz_p1  = sz_xg + sz_xb + sz_w1c;                        // 121,634,816
    const size_t sz_part1 = (size_t)E_NUM * CAP_PAD * D_DIM * 2;         // 37,748,736 (bf16)

    int sshift = 1;
    while (sshift > 0) {
        size_t need = o_dyn + ((sz_part1 << sshift) > sz_p1 ? (sz_part1 << sshift) : sz_p1);
        if (need <= ws_size) break;
        --sshift;
    }
    const int S = 1 << sshift;

    ushort* w2c  = (ushort*)(ws + o_w2c);
    ushort* hbuf = (ushort*)(ws + o_h);
    int*    rt   = (int*)(ws + o_sm);
    int*    te   = (int*)(ws + o_sm + 131072);
    float*  tg   = (float*)(ws + o_sm + 262144);
    int*    inv  = (int*)(ws + o_sm + 393216);
    int*    nk   = (int*)(ws + o_sm + 524288);
    ushort* xg   = (ushort*)(ws + o_dyn);
    ushort* xb   = (ushort*)(ws + o_dyn + sz_xg);
    ushort* w1c  = (ushort*)(ws + o_dyn + sz_xg + sz_xb);
    ushort* part = (ushort*)(ws + o_dyn);   // overlays xg/xb/w1c (dead after GEMM1)

    (void)hipMemsetAsync(inv, 0xFF, (size_t)T_TOK * 2 * 4, stream);   // inv = -1

    router_kernel<<<T_TOK / 4, 256, 0, stream>>>(x, nz, Wr, br, Wn, bn,
                                                 (__hip_bfloat16*)xb, te, tg);
    scan_kernel<<<1, 512, 0, stream>>>(te, tg, rt, inv, nk, out + (size_t)T_TOK * D_DIM);
    // chunk W1 only; W2 chunking is fused into the GEMM1 dispatch below.
    chunk_weights<<<(H_DIM / 64) * (D_DIM / 64) * E_NUM, 256, 0, stream>>>(W1, w1c, D_DIM, H_DIM);
    gather_kernel<<<E_NUM * 128, 256, 0, stream>>>(xb, rt, xg);

    // GEMM1 (2304 blocks) + chunkW2 (8192 blocks) fused: chunk blocks backfill idle
    // CUs/HBM while GEMM1 computes. GEMM2 depends on both either way.
    gemm1_chunk2<<<NG1 + (D_DIM / 64) * (H_DIM / 64) * E_NUM, 256, 0, stream>>>(
        xg, w1c, b1, nk, hbuf, W2, w2c);

    // GEMM2: per expert [2304 x 4096] @ [4096 x 1024], split-K=S -> bf16 partials
    ffn_gemm2<<<dim3(D_DIM / 128, MT, E_NUM << sshift), 256, 0, stream>>>(
        hbuf, w2c, nk, part, sshift, (H_DIM / 32) >> sshift);

    combine_kernel<<<T_TOK, 256, 0, stream>>>(part, inv, tg, b2, S, out);
}

// Round 14
// 509.956 us; speedup vs baseline: 1.1468x; 1.0431x over previous
//
#include <hip/hip_runtime.h>
#include <hip/hip_bf16.h>

#define D_DIM 1024
#define H_DIM 4096
#define E_NUM 8
#define T_TOK 8192
#define CAPN 2252
#define CAP_PAD 2304   // 9 * 256
#define MT 9
#define NG1 2304       // GEMM1 blocks: 32 * 9 * 8

typedef __attribute__((ext_vector_type(8))) short short8;
typedef __attribute__((ext_vector_type(4))) float f32x4;
typedef __attribute__((ext_vector_type(4))) float f4v;
typedef __attribute__((ext_vector_type(4))) ushort u16x4;
typedef const __attribute__((address_space(1))) void* gas_ptr;
typedef __attribute__((address_space(3))) void* las_ptr;

__device__ __forceinline__ unsigned short f2bf(float f) {
    __hip_bfloat16 h = __float2bfloat16(f);
    return __builtin_bit_cast(unsigned short, h);
}
__device__ __forceinline__ float bfu2f(ushort u) {
    unsigned v = (unsigned)u << 16;
    return __builtin_bit_cast(float, v);
}

// -- Weight chunk body: W[e][K][N] f32 -> Wc[e][K/8][N][8] bf16 --
__device__ __forceinline__ void chunk_body(const float* __restrict__ src0,
                                           ushort* __restrict__ dstb,
                                           int K, int N, unsigned i,
                                           float (*tile)[65])
{
    const int nx = N >> 6;
    const int bx = i % nx;
    const unsigned rem = i / nx;
    const int by = rem % (K >> 6);
    const int e  = rem / (K >> 6);
    const int k0 = by * 64, n0 = bx * 64;
    const float* src = src0 + (size_t)e * K * N;
    ushort* dst = dstb + (size_t)e * (K / 8) * N * 8;
    const int t = threadIdx.x;
    const int rr = t >> 4, c4 = (t & 15) * 4;
#pragma unroll
    for (int p = 0; p < 4; ++p) {
        int r = p * 16 + rr;
        f4v v = __builtin_nontemporal_load(
            (const f4v*)(src + (size_t)(k0 + r) * N + n0 + c4));   // read-once f32 stream
        tile[r][c4]     = v.x; tile[r][c4 + 1] = v.y;
        tile[r][c4 + 2] = v.z; tile[r][c4 + 3] = v.w;
    }
    __syncthreads();
    const int n = t & 63, kc = t >> 6;
#pragma unroll
    for (int p = 0; p < 2; ++p) {
        int kcc = p * 4 + kc;
        ushort g[8];
#pragma unroll
        for (int j = 0; j < 8; ++j) g[j] = f2bf(tile[kcc * 8 + j][n]);
        *(short8*)(dst + ((size_t)(k0 / 8 + kcc) * N + n0 + n) * 8) = *(const short8*)g;
    }
}

// ---- Fused: router (blocks 0..2047) + chunk W1 (next 8192 blocks) ----
// Independent work items; the ~18us router hides under W1's ~200MB stream.
__global__ __launch_bounds__(256) void router_chunk1(
    const float* __restrict__ x,
    const float* __restrict__ noise,
    const float* __restrict__ Wr,
    const float* __restrict__ br,
    const float* __restrict__ Wn,
    const float* __restrict__ bn,
    __hip_bfloat16* __restrict__ xb,
    int* __restrict__ tok_e,
    float* __restrict__ tok_g,
    const float* __restrict__ W1,
    ushort* __restrict__ w1c)
{
    __shared__ float tile[64][65];
    const unsigned blk = blockIdx.x;

    if (blk >= 2048) {
        chunk_body(W1, w1c, D_DIM, H_DIM, blk - 2048, tile);
        return;
    }

    const int l = threadIdx.x & 63;
    const int w = threadIdx.x >> 6;
    const int t = blk * 4 + w;
    const float* xr = x + (size_t)t * D_DIM;

    float ar[8] = {0,0,0,0,0,0,0,0};
    float an[8] = {0,0,0,0,0,0,0,0};
#pragma unroll
    for (int i = 0; i < 4; ++i) {
        int d = i * 256 + l * 4;
        f4v xv = __builtin_nontemporal_load((const f4v*)(xr + d));   // read-once stream
        ushort4 xq;
        xq.x = f2bf(xv.x); xq.y = f2bf(xv.y); xq.z = f2bf(xv.z); xq.w = f2bf(xv.w);
        *(ushort4*)(xb + (size_t)t * D_DIM + d) = xq;                // cached: re-read by gather
        float xs[4] = {xv.x, xv.y, xv.z, xv.w};
#pragma unroll
        for (int j = 0; j < 4; ++j) {
            const float* wrp = Wr + (size_t)(d + j) * 8;
            float4 wa = *(const float4*)wrp;
            float4 wb = *(const float4*)(wrp + 4);
            ar[0] = fmaf(xs[j], wa.x, ar[0]); ar[1] = fmaf(xs[j], wa.y, ar[1]);
            ar[2] = fmaf(xs[j], wa.z, ar[2]); ar[3] = fmaf(xs[j], wa.w, ar[3]);
            ar[4] = fmaf(xs[j], wb.x, ar[4]); ar[5] = fmaf(xs[j], wb.y, ar[5]);
            ar[6] = fmaf(xs[j], wb.z, ar[6]); ar[7] = fmaf(xs[j], wb.w, ar[7]);
            const float* wnp = Wn + (size_t)(d + j) * 8;
            float4 na = *(const float4*)wnp;
            float4 nb = *(const float4*)(wnp + 4);
            an[0] = fmaf(xs[j], na.x, an[0]); an[1] = fmaf(xs[j], na.y, an[1]);
            an[2] = fmaf(xs[j], na.z, an[2]); an[3] = fmaf(xs[j], na.w, an[3]);
            an[4] = fmaf(xs[j], nb.x, an[4]); an[5] = fmaf(xs[j], nb.y, an[5]);
            an[6] = fmaf(xs[j], nb.z, an[6]); an[7] = fmaf(xs[j], nb.w, an[7]);
        }
    }
#pragma unroll
    for (int e = 0; e < 8; ++e) {
#pragma unroll
        for (int s = 32; s > 0; s >>= 1) {
            ar[e] += __shfl_xor(ar[e], s, 64);
            an[e] += __shfl_xor(an[e], s, 64);
        }
    }
    if (l == 0) {
        float nv[8];
#pragma unroll
        for (int e = 0; e < 8; ++e) {
            float z = an[e] + bn[e];
            float sp = fmaxf(z, 0.f) + log1pf(expf(-fabsf(z)));   // softplus, stable
            nv[e] = ar[e] + br[e] + noise[(size_t)t * 8 + e] * sp;
        }
        int e0 = 0; float v0 = nv[0];
#pragma unroll
        for (int e = 1; e < 8; ++e) if (nv[e] > v0) { v0 = nv[e]; e0 = e; }  // ties -> lower idx
        int e1 = -1; float v1 = -3.4e38f;
#pragma unroll
        for (int e = 0; e < 8; ++e) if (e != e0 && nv[e] > v1) { v1 = nv[e]; e1 = e; }
        float ex = expf(v1 - v0);          // v1 <= v0, no overflow
        float p0 = 1.f / (1.f + ex);
        float p1 = ex * p0;
        tok_e[2 * t]     = e0; tok_e[2 * t + 1] = e1;
        tok_g[2 * t]     = p0; tok_g[2 * t + 1] = p1;
    }
}

// ---------- Capacity scan: wave e compacts its tokens in order; lb_loss sums ----------
// Every (t,j) slot belongs to exactly one expert wave -> writes inv fully (-1 on drop),
// so no prior memset of inv is needed.
__global__ void scan_kernel(const int* __restrict__ tok_e,
                            const float* __restrict__ tok_g,
                            int* __restrict__ routed,
                            int* __restrict__ inv,
                            int* __restrict__ nkept,
                            float* __restrict__ lb_out)
{
    const int e = threadIdx.x >> 6;
    const int l = threadIdx.x & 63;
    __shared__ float s_g[E_NUM];
    __shared__ int   s_c[E_NUM];

    int run = 0;
    float gsum = 0.f;
    for (int b = 0; b < 8; ++b) {
        int2  ev[16];
        float2 gv[16];
#pragma unroll
        for (int c = 0; c < 16; ++c) {
            int t = (b * 16 + c) * 64 + l;
            ev[c] = ((const int2*)tok_e)[t];
            gv[c] = ((const float2*)tok_g)[t];
        }
#pragma unroll
        for (int c = 0; c < 16; ++c) {
            int t = (b * 16 + c) * 64 + l;
            int j = (ev[c].x == e) ? 0 : ((ev[c].y == e) ? 1 : -1);
            bool sel = (j >= 0);
            unsigned long long m = __ballot(sel);
            if (sel) {
                int pos = run + __popcll(m & ((1ull << l) - 1ull));
                if (pos < CAPN) {
                    routed[e * CAP_PAD + pos] = t;
                    inv[2 * t + j] = e * CAP_PAD + pos;
                } else {
                    inv[2 * t + j] = -1;   // capacity-dropped
                }
                gsum += (j == 0) ? gv[c].x : gv[c].y;   // pre-capacity, matches reference lb
            }
            run += __popcll(m);
        }
    }
#pragma unroll
    for (int s = 32; s > 0; s >>= 1) gsum += __shfl_xor(gsum, s, 64);
    int nk = min(run, CAPN);
    for (int s = nk + l; s < CAP_PAD; s += 64) routed[e * CAP_PAD + s] = 0;  // safe pad
    if (l == 0) { nkept[e] = nk; s_g[e] = gsum; s_c[e] = run; }
    __syncthreads();
    if (threadIdx.x == 0) {
        float lb = 0.f;
        for (int ee = 0; ee < E_NUM; ++ee)
            lb += (s_g[ee] / (float)T_TOK) * ((float)s_c[ee] / (float)T_TOK);
        lb_out[0] = lb * (float)E_NUM;
    }
}

// ---- Gather: xg[e][D/8][CAP_PAD][8] bf16 <- xb[routed[e][m]][dc*8..+8] ----
__global__ void gather_kernel(const ushort* __restrict__ xb,
                              const int* __restrict__ routed,
                              ushort* __restrict__ xg)
{
    const int dc = blockIdx.x & 127;
    const int e  = blockIdx.x >> 7;
    ushort* dst = xg + (size_t)(e * 128 + dc) * CAP_PAD * 8;
    const int* rte = routed + e * CAP_PAD;
#pragma unroll
    for (int p = 0; p < 9; ++p) {
        int m = p * 256 + threadIdx.x;
        int tok = rte[m];
        ulonglong2 v = *(const ulonglong2*)(xb + (size_t)tok * D_DIM + dc * 8);
        *(ulonglong2*)(dst + (size_t)m * 8) = v;   // cached: re-read by GEMM1
    }
}

// ------ GEMM1 (256x128 block, wave 128x64, BK=32, 3-stage) fused with chunkW2 ------
__global__ __launch_bounds__(256, 2) void gemm1_chunk2(
    const ushort* __restrict__ A,     // xg [E][128][CAP_PAD][8]
    const ushort* __restrict__ Bt,    // w1c [E][128][H][8]
    const float* __restrict__ bias,
    const int* __restrict__ nkept,
    ushort* __restrict__ outH,
    const float* __restrict__ W2,
    ushort* __restrict__ w2c)
{
    __shared__ ushort lds[36864];   // 72 KiB (GEMM); chunk aliases 16.6 KiB of it
    const unsigned blk = blockIdx.x;

    if (blk >= NG1) {
        chunk_body(W2, w2c, H_DIM, D_DIM, blk - NG1, (float(*)[65])lds);
        return;
    }

    constexpr int ND = H_DIM;
    constexpr int NC = D_DIM / 8;
    constexpr int nkt = D_DIM / 32;

    unsigned sw = (blk & 7) * (NG1 >> 3) + (blk >> 3);
    unsigned bn = sw % (H_DIM / 128);
    unsigned t1 = sw / (H_DIM / 128);
    unsigned bm = t1 % MT;
    unsigned e  = t1 / MT;

    const int m0 = (int)bm * 256, n0 = (int)bn * 128;
    if (m0 >= nkept[e]) return;

    const int tid  = threadIdx.x;
    const int lane = tid & 63;
    const int w    = tid >> 6;
    const int aw   = w << 10;
    const int bci  = tid >> 7;
    const int bw   = (w & 1) << 10;

    const size_t sAc = (size_t)CAP_PAD * 8;
    const size_t sBc = (size_t)ND * 8;
    const size_t tsA = 4 * sAc;
    const size_t tsB = 4 * sBc;

    const ushort* Ae = A  + ((size_t)e * NC * CAP_PAD + (size_t)(m0 + tid)) * 8;
    const ushort* Be = Bt + ((size_t)e * NC * ND + (size_t)(n0 + (tid & 127))) * 8
                          + (size_t)bci * sBc;

    auto gl = [&](const ushort* g, int ldsbyte) {
        __builtin_amdgcn_global_load_lds((gas_ptr)g, (las_ptr)((char*)lds + ldsbyte), 16, 0, 0);
    };
    auto issueA = [&](size_t off, int stB) {
        gl(Ae + off,           stB + 0 * 4096 + aw);
        gl(Ae + off + sAc,     stB + 1 * 4096 + aw);
        gl(Ae + off + 2 * sAc, stB + 2 * 4096 + aw);
        gl(Ae + off + 3 * sAc, stB + 3 * 4096 + aw);
    };
    auto issueB = [&](size_t off, int stB) {
        gl(Be + off,           stB + 16384 + (0 + bci) * 2048 + bw);
        gl(Be + off + 2 * sBc, stB + 16384 + (2 + bci) * 2048 + bw);
    };

    issueA(0, 0);        issueB(0, 0);
    issueA(tsA, 24576);  issueB(tsB, 24576);
    asm volatile("s_waitcnt vmcnt(6)" ::: "memory");
    __builtin_amdgcn_s_barrier();

    f32x4 acc[8][4] = {};
    const int wm = (w >> 1) * 128;
    const int wn = (w & 1) * 64;
    const int fr = lane & 15;
    const int fq = lane >> 4;

    int rdS = 0;
    int wrB = 49152;
    size_t oA = 2 * tsA;
    size_t oB = 2 * tsB;

    for (int kt = 0; kt < nkt; ++kt) {
        const ushort* Ard = lds + rdS;
        const ushort* Brd = lds + rdS + 8192;

        short8 af[8], bfr[4];
#pragma unroll
        for (int j = 0; j < 4; ++j)
            bfr[j] = *(const short8*)(Brd + fq * 1024 + (wn + j * 16 + fr) * 8);
#pragma unroll
        for (int i = 0; i < 8; ++i)
            af[i] = *(const short8*)(Ard + fq * 2048 + (wm + i * 16 + fr) * 8);

        issueA(oA, wrB);
        issueB(oB, wrB);

        __builtin_amdgcn_s_setprio(1);
#pragma unroll
        for (int i = 0; i < 8; ++i)
#pragma unroll
            for (int j = 0; j < 4; ++j)
                acc[i][j] = __builtin_amdgcn_mfma_f32_16x16x32_bf16(af[i], bfr[j], acc[i][j], 0, 0, 0);
        __builtin_amdgcn_s_setprio(0);

        asm volatile("s_waitcnt vmcnt(6)" ::: "memory");
        __builtin_amdgcn_s_barrier();

        rdS = (rdS == 24576) ? 0 : rdS + 12288;
        wrB = (wrB == 49152) ? 0 : wrB + 24576;
        if (kt < nkt - 3) { oA += tsA; oB += tsB; }
    }

#pragma unroll
    for (int j = 0; j < 4; ++j) {
        int nc = n0 + wn + j * 16 + fr;
        float bv = bias[e * ND + nc];
#pragma unroll
        for (int i = 0; i < 8; ++i) {
            int mr = m0 + wm + i * 16 + (fq << 2);
#pragma unroll
            for (int r = 0; r < 4; ++r) {
                float v = fmaxf(acc[i][j][r] + bv, 0.f);
                outH[(((size_t)e * 512 + (nc >> 3)) * CAP_PAD + mr + r) * 8 + (nc & 7)] = f2bf(v);
            }
        }
    }
}

// ------ GEMM2: 256x128 block, wave 128x64, BK=32, 3-stage; bf16 split-K partials ------
__global__ __launch_bounds__(256, 2) void ffn_gemm2(
    const ushort* __restrict__ A,     // hbuf [E][512][CAP_PAD][8]
    const ushort* __restrict__ Bt,    // w2c [E][512][D][8]
    const int* __restrict__ nkept,
    ushort* __restrict__ outP,        // bf16 partials [S][E][CAP_PAD][D]
    int sshift, int nkt)
{
    constexpr int KD = H_DIM;
    constexpr int ND = D_DIM;
    constexpr int NC = KD / 8;
    __shared__ ushort lds[36864];

    unsigned total = gridDim.x * gridDim.y * gridDim.z;
    unsigned flat  = blockIdx.x + gridDim.x * (blockIdx.y + gridDim.y * blockIdx.z);
    unsigned sw    = (flat & 7) * (total >> 3) + (flat >> 3);
    unsigned bn    = sw % gridDim.x;
    unsigned t1    = sw / gridDim.x;
    unsigned bm    = t1 % gridDim.y;
    unsigned bz    = t1 / gridDim.y;

    const int e  = (int)(bz >> sshift);
    const int sp = (int)(bz & ((1u << sshift) - 1u));
    const int m0 = (int)bm * 256, n0 = (int)bn * 128;
    if (m0 >= nkept[e]) return;
    const int kc0 = sp * (nkt << 2);

    const int tid  = threadIdx.x;
    const int lane = tid & 63;
    const int w    = tid >> 6;
    const int aw   = w << 10;
    const int bci  = tid >> 7;
    const int bw   = (w & 1) << 10;

    const size_t sAc = (size_t)CAP_PAD * 8;
    const size_t sBc = (size_t)ND * 8;
    const size_t tsA = 4 * sAc;
    const size_t tsB = 4 * sBc;

    const ushort* Ae = A  + ((size_t)e * NC * CAP_PAD + (size_t)(m0 + tid)) * 8
                          + (size_t)kc0 * sAc;
    const ushort* Be = Bt + ((size_t)e * NC * ND + (size_t)(n0 + (tid & 127))) * 8
                          + (size_t)(kc0 + bci) * sBc;

    auto gl = [&](const ushort* g, int ldsbyte) {
        __builtin_amdgcn_global_load_lds((gas_ptr)g, (las_ptr)((char*)lds + ldsbyte), 16, 0, 0);
    };
    auto issueA = [&](size_t off, int stB) {
        gl(Ae + off,           stB + 0 * 4096 + aw);
        gl(Ae + off + sAc,     stB + 1 * 4096 + aw);
        gl(Ae + off + 2 * sAc, stB + 2 * 4096 + aw);
        gl(Ae + off + 3 * sAc, stB + 3 * 4096 + aw);
    };
    auto issueB = [&](size_t off, int stB) {
        gl(Be + off,           stB + 16384 + (0 + bci) * 2048 + bw);
        gl(Be + off + 2 * sBc, stB + 16384 + (2 + bci) * 2048 + bw);
    };

    issueA(0, 0);        issueB(0, 0);
    issueA(tsA, 24576);  issueB(tsB, 24576);
    asm volatile("s_waitcnt vmcnt(6)" ::: "memory");
    __builtin_amdgcn_s_barrier();

    f32x4 acc[8][4] = {};
    const int wm = (w >> 1) * 128;
    const int wn = (w & 1) * 64;
    const int fr = lane & 15;
    const int fq = lane >> 4;

    int rdS = 0;
    int wrB = 49152;
    size_t oA = 2 * tsA;
    size_t oB = 2 * tsB;

    for (int kt = 0; kt < nkt; ++kt) {
        const ushort* Ard = lds + rdS;
        const ushort* Brd = lds + rdS + 8192;

        short8 af[8], bfr[4];
#pragma unroll
        for (int j = 0; j < 4; ++j)
            bfr[j] = *(const short8*)(Brd + fq * 1024 + (wn + j * 16 + fr) * 8);
#pragma unroll
        for (int i = 0; i < 8; ++i)
            af[i] = *(const short8*)(Ard + fq * 2048 + (wm + i * 16 + fr) * 8);

        issueA(oA, wrB);
        issueB(oB, wrB);

        __builtin_amdgcn_s_setprio(1);
#pragma unroll
        for (int i = 0; i < 8; ++i)
#pragma unroll
            for (int j = 0; j < 4; ++j)
                acc[i][j] = __builtin_amdgcn_mfma_f32_16x16x32_bf16(af[i], bfr[j], acc[i][j], 0, 0, 0);
        __builtin_amdgcn_s_setprio(0);

        asm volatile("s_waitcnt vmcnt(6)" ::: "memory");
        __builtin_amdgcn_s_barrier();

        rdS = (rdS == 24576) ? 0 : rdS + 12288;
        wrB = (wrB == 49152) ? 0 : wrB + 24576;
        if (kt < nkt - 3) { oA += tsA; oB += tsB; }
    }

#pragma unroll
    for (int j = 0; j < 4; ++j) {
        int nc = n0 + wn + j * 16 + fr;
#pragma unroll
        for (int i = 0; i < 8; ++i) {
            int mr = m0 + wm + i * 16 + (fq << 2);
#pragma unroll
            for (int r = 0; r < 4; ++r)
                outP[((size_t)(sp * E_NUM + e) * CAP_PAD + mr + r) * D_DIM + nc] =
                    f2bf(acc[i][j][r]);
        }
    }
}

// -------- Final combine: out[t] = sum_j gate_j * (sum_s part[s][inv_j] + b2[e_j]) --------
__global__ void combine_kernel(const ushort* __restrict__ part,
                               const int* __restrict__ inv,
                               const float* __restrict__ tok_g,
                               const float* __restrict__ b2,
                               int S,
                               float* __restrict__ out)
{
    const int t = blockIdx.x;
    const int d = threadIdx.x * 4;
    f4v r = {0.f, 0.f, 0.f, 0.f};
#pragma unroll
    for (int j = 0; j < 2; ++j) {
        int i = inv[2 * t + j];
        if (i >= 0) {
            float g = tok_g[2 * t + j];
            int e = i / CAP_PAD;
            f4v a = *(const f4v*)(b2 + (size_t)e * D_DIM + d);
            for (int s = 0; s < S; ++s) {
                u16x4 p = __builtin_nontemporal_load(
                    (const u16x4*)(part + ((size_t)s * E_NUM * CAP_PAD + i) * D_DIM + d));
                a.x += bfu2f(p.x); a.y += bfu2f(p.y);
                a.z += bfu2f(p.z); a.w += bfu2f(p.w);
            }
            r += g * a;
        }
    }
    __builtin_nontemporal_store(r, (f4v*)(out + (size_t)t * D_DIM + d));
}

extern "C" void kernel_launch(void* const* d_in, const int* in_sizes, int n_in,
                              void* d_out, int out_size, void* d_ws, size_t ws_size,
                              hipStream_t stream)
{
    const float* x  = (const float*)d_in[0];
    const float* nz = (const float*)d_in[1];
    const float* Wr = (const float*)d_in[2];
    const float* br = (const float*)d_in[3];
    const float* Wn = (const float*)d_in[4];
    const float* bn = (const float*)d_in[5];
    const float* W1 = (const float*)d_in[6];
    const float* b1 = (const float*)d_in[7];
    const float* W2 = (const float*)d_in[8];
    const float* b2 = (const float*)d_in[9];
    float* out = (float*)d_out;
    char* ws = (char*)d_ws;

    // Workspace: [w2c 64MB][hbuf 144MB][small 1MB][dyn]
    //   dyn phase1: xg(36MB) + xb(16MB) + w1c(64MB)   (all dead after GEMM1)
    //   dyn phase2: part bf16 (S * 37.7MB)            (overlays phase1)
    const size_t sz_w2c = (size_t)E_NUM * (H_DIM / 8) * D_DIM * 8 * 2;   // 67,108,864
    const size_t sz_h   = (size_t)E_NUM * 512 * CAP_PAD * 8 * 2;         // 150,994,944
    const size_t o_w2c  = 0;
    const size_t o_h    = o_w2c + sz_w2c;
    const size_t o_sm   = o_h + sz_h;
    const size_t o_dyn  = o_sm + (1u << 20);
    const size_t sz_xg  = (size_t)E_NUM * 128 * CAP_PAD * 8 * 2;         // 37,748,736
    const size_t sz_xb  = (size_t)T_TOK * D_DIM * 2;                     // 16,777,216
    const size_t sz_w1c = (size_t)E_NUM * (D_DIM / 8) * H_DIM * 8 * 2;   // 67,108,864
    const size_t sz_p1  = sz_xg + sz_xb + sz_w1c;                        // 121,634,816
    const size_t sz_part1 = (size_t)E_NUM * CAP_PAD * D_DIM * 2;         // 37,748,736 (bf16)

    int sshift = 1;
    while (sshift > 0) {
        size_t need = o_dyn + ((sz_part1 << sshift) > sz_p1 ? (sz_part1 << sshift) : sz_p1);
        if (need <= ws_size) break;
        --sshift;
    }
    const int S = 1 << sshift;

    ushort* w2c  = (ushort*)(ws + o_w2c);
    ushort* hbuf = (ushort*)(ws + o_h);
    int*    rt   = (int*)(ws + o_sm);
    int*    te   = (int*)(ws + o_sm + 131072);
    float*  tg   = (float*)(ws + o_sm + 262144);
    int*    inv  = (int*)(ws + o_sm + 393216);
    int*    nk   = (int*)(ws + o_sm + 524288);
    ushort* xg   = (ushort*)(ws + o_dyn);
    ushort* xb   = (ushort*)(ws + o_dyn + sz_xg);
    ushort* w1c  = (ushort*)(ws + o_dyn + sz_xg + sz_xb);
    ushort* part = (ushort*)(ws + o_dyn);   // overlays xg/xb/w1c (dead after GEMM1)

    // Fused router + chunkW1 (independent; router hides under W1 stream)
    router_chunk1<<<2048 + (H_DIM / 64) * (D_DIM / 64) * E_NUM, 256, 0, stream>>>(
        x, nz, Wr, br, Wn, bn, (__hip_bfloat16*)xb, te, tg, W1, w1c);

    // scan fully populates inv (writes -1 for dropped slots) -> no memset needed
    scan_kernel<<<1, 512, 0, stream>>>(te, tg, rt, inv, nk, out + (size_t)T_TOK * D_DIM);
    gather_kernel<<<E_NUM * 128, 256, 0, stream>>>(xb, rt, xg);

    // GEMM1 (2304 blocks) + chunkW2 (8192 blocks) fused
    gemm1_chunk2<<<NG1 + (D_DIM / 64) * (H_DIM / 64) * E_NUM, 256, 0, stream>>>(
        xg, w1c, b1, nk, hbuf, W2, w2c);

    // GEMM2: per expert [2304 x 4096] @ [4096 x 1024], split-K=S -> bf16 partials
    ffn_gemm2<<<dim3(D_DIM / 128, MT, E_NUM << sshift), 256, 0, stream>>>(
        hbuf, w2c, nk, part, sshift, (H_DIM / 32) >> sshift);

    combine_kernel<<<T_TOK, 256, 0, stream>>>(part, inv, tg, b2, S, out);
}